// Round 16
// baseline (867.554 us; speedup 1.0000x reference)
//
#include <hip/hip_runtime.h>

// ---------------------------------------------------------------------------
// StructureEncoder — MFMA bf16 GEMMs, CSR gather aggregation (bf16, ILP-16),
// bucketed two-pass CSR build (kills the 105MB write amplification of the
// single-pass random-scatter csr_fill), BN+ReLU fused into GEMM A-load.
// ---------------------------------------------------------------------------

#define BK_SHIFT 7            // 128 nodes per bucket
#define BK_CAP   2560         // staging capacity per bucket (mean 2048, ~11 sigma)

typedef __attribute__((ext_vector_type(8))) short bf16x8;
typedef __attribute__((ext_vector_type(4))) float f32x4;

__device__ inline unsigned short f2bf(float f) {
    unsigned u = __float_as_uint(f);
    unsigned r = u + 0x7FFFu + ((u >> 16) & 1u);   // RNE
    return (unsigned short)(r >> 16);
}
__device__ inline float bf2f(unsigned u16) {
    return __uint_as_float(u16 << 16);
}

__global__ void k_edetect(const int* __restrict__ ei, int n, int* __restrict__ flag) {
    if (threadIdx.x == 0 && blockIdx.x == 0) {
        int is64 = 1;
        for (int i = 0; i < 64; ++i) {
            if (ei[2 * i + 1] != 0 || (unsigned)ei[2 * i] >= (unsigned)n) { is64 = 0; break; }
        }
        *flag = is64;
    }
}

__global__ __launch_bounds__(256) void deg_count(const int* __restrict__ ei,
                                                 const int* __restrict__ eflag,
                                                 unsigned* __restrict__ deg, int e, int n) {
    int i = blockIdx.x * 256 + threadIdx.x;
    if (i >= e) return;
    int d = (*eflag) ? ei[2 * (size_t)e + 2 * (size_t)i] : ei[(size_t)e + i];
    if ((unsigned)d < (unsigned)n) atomicAdd(&deg[d], 1u);
}

__global__ __launch_bounds__(256) void k_dis(const unsigned* __restrict__ deg,
                                             float* __restrict__ dis, int n) {
    int i = blockIdx.x * 256 + threadIdx.x;
    if (i < n) dis[i] = rsqrtf((float)deg[i] + 1.0f);
}

// ---- ordered exclusive prefix sum of deg -> starts (3 small kernels) -------

__global__ __launch_bounds__(256) void scan_chunk_sum(const unsigned* __restrict__ deg,
                                                      unsigned* __restrict__ bsum, int n) {
    int t = threadIdx.x, i = blockIdx.x * 256 + t;
    __shared__ unsigned sh[256];
    sh[t] = (i < n) ? deg[i] : 0u;
    __syncthreads();
    for (int o = 128; o > 0; o >>= 1) {
        if (t < o) sh[t] += sh[t + o];
        __syncthreads();
    }
    if (t == 0) bsum[blockIdx.x] = sh[0];
}

__global__ void scan_blocksums(unsigned* __restrict__ bsum, int nb) {
    __shared__ unsigned tmp[512];
    int t = threadIdx.x;                  // 512 threads
    unsigned v = (t < nb) ? bsum[t] : 0u;
    tmp[t] = v;
    __syncthreads();
    for (int o = 1; o < 512; o <<= 1) {
        unsigned u = (t >= o) ? tmp[t - o] : 0u;
        __syncthreads();
        tmp[t] += u;
        __syncthreads();
    }
    if (t < nb) bsum[t] = tmp[t] - v;     // exclusive
}

__global__ __launch_bounds__(256) void scan_chunk_excl(const unsigned* __restrict__ deg,
                                                       const unsigned* __restrict__ boff,
                                                       unsigned* __restrict__ starts, int n) {
    __shared__ unsigned tmp[256];
    int t = threadIdx.x, i = blockIdx.x * 256 + t;
    unsigned v = (i < n) ? deg[i] : 0u;
    tmp[t] = v;
    __syncthreads();
    for (int o = 1; o < 256; o <<= 1) {
        unsigned u = (t >= o) ? tmp[t - o] : 0u;
        __syncthreads();
        tmp[t] += u;
        __syncthreads();
    }
    if (i < n) starts[i] = boff[blockIdx.x] + tmp[t] - v;
}

// ---- bucketed CSR build: stage (append to dst-bucket), then fill ----------

__global__ __launch_bounds__(256) void stage_edges(const int* __restrict__ ei,
                                                   const int* __restrict__ eflag,
                                                   unsigned* __restrict__ bcur,
                                                   uint2* __restrict__ staged, int e, int n) {
    int i = blockIdx.x * 256 + threadIdx.x;
    if (i >= e) return;
    int s, d;
    if (*eflag) {
        s = ei[2 * (size_t)i];
        d = ei[2 * (size_t)e + 2 * (size_t)i];
    } else {
        s = ei[i];
        d = ei[(size_t)e + i];
    }
    if ((unsigned)s >= (unsigned)n || (unsigned)d >= (unsigned)n) return;
    int b = d >> BK_SHIFT;
    unsigned pos = atomicAdd(&bcur[b], 1u);
    if (pos < BK_CAP) staged[(size_t)b * BK_CAP + pos] = make_uint2((unsigned)s, (unsigned)d);
}

__global__ __launch_bounds__(256) void fill_csr(const uint2* __restrict__ staged,
                                                const unsigned* __restrict__ bcur,
                                                const unsigned* __restrict__ starts,
                                                int* __restrict__ csr_src, int n) {
    int b = blockIdx.x, t = threadIdx.x;
    int nb0 = b << BK_SHIFT;
    __shared__ unsigned lcur[1 << BK_SHIFT];
    if (t < (1 << BK_SHIFT)) {
        int node = nb0 + t;
        lcur[t] = (node < n) ? starts[node] : 0u;
    }
    __syncthreads();
    unsigned cnt = bcur[b];
    if (cnt > BK_CAP) cnt = BK_CAP;
    for (unsigned i = t; i < cnt; i += 256) {
        uint2 ed = staged[(size_t)b * BK_CAP + i];
        unsigned slot = atomicAdd(&lcur[ed.y - nb0], 1u);
        csr_src[slot] = (int)ed.x;
    }
}

// ---- weight prep: Wt[c][k] = bf16(W[k][c]) for W1, W2, [Wmu|Wlv]; bcat -----

__global__ __launch_bounds__(256) void prep_weights(const float* __restrict__ W1,
                                                    const float* __restrict__ W2,
                                                    const float* __restrict__ Wmu,
                                                    const float* __restrict__ Wlv,
                                                    const float* __restrict__ bmu,
                                                    const float* __restrict__ blv,
                                                    unsigned short* __restrict__ Wt1,
                                                    unsigned short* __restrict__ Wt2,
                                                    unsigned short* __restrict__ Wtc,
                                                    float* __restrict__ bcat) {
    int idx = blockIdx.x * 256 + threadIdx.x;
    if (idx < 16384) {
        int c = idx >> 7, k = idx & 127;
        Wt1[idx] = f2bf(W1[(size_t)k * 128 + c]);
    } else if (idx < 32768) {
        int t = idx - 16384, c = t >> 7, k = t & 127;
        Wt2[t] = f2bf(W2[(size_t)k * 128 + c]);
    } else if (idx < 49152) {
        int t = idx - 32768, c = t >> 7, k = t & 127;
        float v = (c < 64) ? Wmu[(size_t)k * 64 + c] : Wlv[(size_t)k * 64 + (c - 64)];
        Wtc[t] = f2bf(v);
    }
    if (idx < 128) bcat[idx] = (idx < 64) ? bmu[idx] : blv[idx - 64];
}

// ---- aggregation (gather, bf16 hW, ILP-16/8/4/1): one wave per node --------

__global__ __launch_bounds__(256) void aggregate(const unsigned* __restrict__ hWb,  // bf16x2
                                                 const int* __restrict__ csr_src,
                                                 const unsigned* __restrict__ starts,
                                                 const unsigned* __restrict__ deg,
                                                 const float* __restrict__ dis,
                                                 const float* __restrict__ bias,
                                                 float* __restrict__ outh, int n) {
    int node = blockIdx.x * 4 + (threadIdx.x >> 6);
    int lane = threadIdx.x & 63;
    if (node >= n) return;
    unsigned s0 = starts[node], dn = deg[node];
    float ax = 0.f, ay = 0.f;
    unsigned j = 0;
    for (; j + 16 <= dn; j += 16) {
        int si[16]; unsigned vv[16]; float ww[16];
#pragma unroll
        for (int q = 0; q < 16; ++q) si[q] = csr_src[s0 + j + q];
#pragma unroll
        for (int q = 0; q < 16; ++q) vv[q] = hWb[(size_t)si[q] * 64 + lane];
#pragma unroll
        for (int q = 0; q < 16; ++q) ww[q] = dis[si[q]];
#pragma unroll
        for (int q = 0; q < 16; ++q) {
            ax = fmaf(bf2f(vv[q] & 0xFFFFu), ww[q], ax);
            ay = fmaf(bf2f(vv[q] >> 16), ww[q], ay);
        }
    }
    for (; j + 8 <= dn; j += 8) {
        int si[8]; unsigned vv[8]; float ww[8];
#pragma unroll
        for (int q = 0; q < 8; ++q) si[q] = csr_src[s0 + j + q];
#pragma unroll
        for (int q = 0; q < 8; ++q) vv[q] = hWb[(size_t)si[q] * 64 + lane];
#pragma unroll
        for (int q = 0; q < 8; ++q) ww[q] = dis[si[q]];
#pragma unroll
        for (int q = 0; q < 8; ++q) {
            ax = fmaf(bf2f(vv[q] & 0xFFFFu), ww[q], ax);
            ay = fmaf(bf2f(vv[q] >> 16), ww[q], ay);
        }
    }
    for (; j + 4 <= dn; j += 4) {
        int si[4]; unsigned vv[4]; float ww[4];
#pragma unroll
        for (int q = 0; q < 4; ++q) si[q] = csr_src[s0 + j + q];
#pragma unroll
        for (int q = 0; q < 4; ++q) vv[q] = hWb[(size_t)si[q] * 64 + lane];
#pragma unroll
        for (int q = 0; q < 4; ++q) ww[q] = dis[si[q]];
#pragma unroll
        for (int q = 0; q < 4; ++q) {
            ax = fmaf(bf2f(vv[q] & 0xFFFFu), ww[q], ax);
            ay = fmaf(bf2f(vv[q] >> 16), ww[q], ay);
        }
    }
    for (; j < dn; ++j) {
        int      s = csr_src[s0 + j];
        float    w = dis[s];
        unsigned v = hWb[(size_t)s * 64 + lane];
        ax = fmaf(bf2f(v & 0xFFFFu), w, ax);
        ay = fmaf(bf2f(v >> 16), w, ay);
    }
    float dii = dis[node];
    unsigned vs = hWb[(size_t)node * 64 + lane];
    float rx = fmaf(dii, ax, dii * dii * bf2f(vs & 0xFFFFu)) + bias[lane * 2];
    float ry = fmaf(dii, ay, dii * dii * bf2f(vs >> 16)) + bias[lane * 2 + 1];
    *(float2*)(outh + (size_t)node * 128 + lane * 2) = make_float2(rx, ry);
}

// ---- BatchNorm statistics --------------------------------------------------

__global__ __launch_bounds__(256) void bn_stats(const float* __restrict__ h,
                                                float* __restrict__ sums, int n) {
    int tid = threadIdx.x;
    int c = tid & 127, half = tid >> 7;
    float s = 0.f, s2 = 0.f;
    for (int r = blockIdx.x * 2 + half; r < n; r += gridDim.x * 2) {
        float v = h[(size_t)r * 128 + c];
        s += v;
        s2 = fmaf(v, v, s2);
    }
    __shared__ float sh[256];
    sh[tid] = s;
    __syncthreads();
    if (tid < 128) atomicAdd(&sums[tid], sh[tid] + sh[tid + 128]);
    __syncthreads();
    sh[tid] = s2;
    __syncthreads();
    if (tid < 128) atomicAdd(&sums[128 + tid], sh[tid] + sh[tid + 128]);
}

__global__ void bn_final(const float* __restrict__ sums, const float* __restrict__ g,
                         const float* __restrict__ be, float* __restrict__ bnp, int n) {
    int c = threadIdx.x;                            // 128 threads
    float inv_n = 1.0f / (float)n;
    float mean = sums[c] * inv_n;
    float var  = sums[128 + c] * inv_n - mean * mean;
    float sc   = g[c] * rsqrtf(var + 1e-5f);
    bnp[c]       = sc;
    bnp[128 + c] = be[c] - mean * sc;
}

// ---- MFMA GEMM: C[M,128] = bnrelu(A)[M,128] @ W[128,128] -------------------

template <bool HEAD>
__global__ __launch_bounds__(256, 4) void gemm_mfma(const float* __restrict__ A,
                                                    const unsigned short* __restrict__ Wt,
                                                    const float* __restrict__ bnp,
                                                    const float* __restrict__ bias,
                                                    void* __restrict__ Cv, int nrows) {
    __shared__ float Cl[64][130];
    __shared__ float bnsc[128], bnsh[128];

    const int tid  = threadIdx.x;
    const int lane = tid & 63;
    const int wv   = tid >> 6;
    const int rowbase = blockIdx.x * 64;
    const bool has_bn = (bnp != nullptr);
    if (has_bn && tid < 128) {
        bnsc[tid] = bnp[tid];
        bnsh[tid] = bnp[128 + tid];
    }
    __syncthreads();

    const int ar = rowbase + wv * 16 + (lane & 15);
    const int kg = (lane >> 4) * 8;
    const int bc = lane & 15;

    f32x4 acc[8];
#pragma unroll
    for (int t = 0; t < 8; ++t) acc[t] = {0.f, 0.f, 0.f, 0.f};

#pragma unroll
    for (int k0 = 0; k0 < 128; k0 += 32) {
        float va[8];
        if (ar < nrows) {
            float4 a0 = *(const float4*)(A + (size_t)ar * 128 + k0 + kg);
            float4 a1 = *(const float4*)(A + (size_t)ar * 128 + k0 + kg + 4);
            va[0] = a0.x; va[1] = a0.y; va[2] = a0.z; va[3] = a0.w;
            va[4] = a1.x; va[5] = a1.y; va[6] = a1.z; va[7] = a1.w;
        } else {
#pragma unroll
            for (int i = 0; i < 8; ++i) va[i] = 0.f;
        }
        if (has_bn) {
#pragma unroll
            for (int i = 0; i < 8; ++i) {
                int k = k0 + kg + i;
                va[i] = fmaxf(0.f, fmaf(va[i], bnsc[k], bnsh[k]));
            }
        }
        bf16x8 af;
#pragma unroll
        for (int i = 0; i < 8; ++i) af[i] = (short)f2bf(va[i]);

#pragma unroll
        for (int ct = 0; ct < 8; ++ct) {
            bf16x8 bf = *(const bf16x8*)(Wt + (size_t)(ct * 16 + bc) * 128 + k0 + kg);
            acc[ct] = __builtin_amdgcn_mfma_f32_16x16x32_bf16(af, bf, acc[ct], 0, 0, 0);
        }
    }

    const int lr = wv * 16 + ((lane >> 4) << 2);
#pragma unroll
    for (int ct = 0; ct < 8; ++ct)
#pragma unroll
        for (int r = 0; r < 4; ++r)
            Cl[lr + r][ct * 16 + bc] = acc[ct][r];
    __syncthreads();

    const int row = tid >> 2;
    const int c0  = (tid & 3) * 32;
    const int gr  = rowbase + row;
    if (gr < nrows) {
        if (!HEAD) {
            unsigned* C = (unsigned*)Cv;
#pragma unroll
            for (int u = 0; u < 4; ++u) {
                int cb = c0 + u * 8;
                unsigned o0 = (unsigned)f2bf(Cl[row][cb + 0]) | ((unsigned)f2bf(Cl[row][cb + 1]) << 16);
                unsigned o1 = (unsigned)f2bf(Cl[row][cb + 2]) | ((unsigned)f2bf(Cl[row][cb + 3]) << 16);
                unsigned o2 = (unsigned)f2bf(Cl[row][cb + 4]) | ((unsigned)f2bf(Cl[row][cb + 5]) << 16);
                unsigned o3 = (unsigned)f2bf(Cl[row][cb + 6]) | ((unsigned)f2bf(Cl[row][cb + 7]) << 16);
                uint4 o4 = {o0, o1, o2, o3};
                *(uint4*)(C + (size_t)gr * 64 + cb / 2) = o4;
            }
        } else {
            float* mu = (float*)Cv;
            float* lv = mu + (size_t)nrows * 64;
            float* dst = (c0 < 64) ? (mu + (size_t)gr * 64 + c0) : (lv + (size_t)gr * 64 + (c0 - 64));
#pragma unroll
            for (int u = 0; u < 8; ++u) {
                int cb = c0 + u * 4;
                float4 o = make_float4(Cl[row][cb + 0] + bias[cb + 0],
                                       Cl[row][cb + 1] + bias[cb + 1],
                                       Cl[row][cb + 2] + bias[cb + 2],
                                       Cl[row][cb + 3] + bias[cb + 3]);
                *(float4*)(dst + u * 4) = o;
            }
        }
    }
}

// ---------------------------------------------------------------------------

extern "C" void kernel_launch(void* const* d_in, const int* in_sizes, int n_in,
                              void* d_out, int out_size, void* d_ws, size_t ws_size,
                              hipStream_t stream) {
    const float* x   = (const float*)d_in[0];
    const int*   ei  = (const int*)d_in[1];
    const float* W1  = (const float*)d_in[2];
    const float* b1  = (const float*)d_in[3];
    const float* g1  = (const float*)d_in[4];
    const float* be1 = (const float*)d_in[5];
    const float* W2  = (const float*)d_in[6];
    const float* b2  = (const float*)d_in[7];
    const float* g2  = (const float*)d_in[8];
    const float* be2 = (const float*)d_in[9];
    const float* Wmu = (const float*)d_in[10];
    const float* bmu = (const float*)d_in[11];
    const float* Wlv = (const float*)d_in[12];
    const float* blv = (const float*)d_in[13];

    const int n = in_sizes[0] / 128;   // 100000
    const int e = in_sizes[1] / 2;     // 1600000

    const int nchunks  = (n + 255) / 256;           // 391 scan chunks
    const int nbuckets = (n + (1 << BK_SHIFT) - 1) >> BK_SHIFT;   // 782

    char* ws = (char*)d_ws;
    size_t off = 0;
    auto alloc = [&](size_t bytes) {
        void* p = ws + off;
        off = (off + bytes + 255) & ~(size_t)255;
        return p;
    };
    float*          bufH    = (float*)alloc((size_t)n * 128 * 4);          // 51.2 MB
    unsigned*       hWb     = (unsigned*)alloc((size_t)n * 64 * 4);        // 25.6 MB
    int*            csr_src = (int*)alloc((size_t)e * 4);                  //  6.4 MB
    uint2*          staged  = (uint2*)alloc((size_t)nbuckets * BK_CAP * 8);// 16.0 MB
    unsigned*       deg     = (unsigned*)alloc((size_t)n * 4);
    float*          dis     = (float*)alloc((size_t)n * 4);
    unsigned*       starts  = (unsigned*)alloc((size_t)n * 4);
    unsigned*       bcur    = (unsigned*)alloc((size_t)nbuckets * 4);
    unsigned*       bsum    = (unsigned*)alloc((size_t)nchunks * 4);
    int*            eflag   = (int*)alloc(256);
    float*          sums    = (float*)alloc(256 * 4);
    float*          bnp     = (float*)alloc(256 * 4);
    unsigned short* Wt1     = (unsigned short*)alloc(16384 * 2);
    unsigned short* Wt2     = (unsigned short*)alloc(16384 * 2);
    unsigned short* Wtc     = (unsigned short*)alloc(16384 * 2);
    float*          bcat    = (float*)alloc(128 * 4);
    // total ~100.5 MB (ws verified >= 103.2 MB in round 6)

    const int eb = (e + 255) / 256;
    const int ab = (n + 3) / 4;
    const int gg = (n + 63) / 64;

    // prep: weights, degree, ordered starts (scan), bucketed CSR
    hipMemsetAsync(deg, 0, (size_t)n * 4, stream);
    hipMemsetAsync(bcur, 0, (size_t)nbuckets * 4, stream);
    prep_weights<<<192, 256, 0, stream>>>(W1, W2, Wmu, Wlv, bmu, blv, Wt1, Wt2, Wtc, bcat);
    k_edetect<<<1, 64, 0, stream>>>(ei, n, eflag);
    deg_count<<<eb, 256, 0, stream>>>(ei, eflag, deg, e, n);
    k_dis<<<nchunks, 256, 0, stream>>>(deg, dis, n);
    scan_chunk_sum<<<nchunks, 256, 0, stream>>>(deg, bsum, n);
    scan_blocksums<<<1, 512, 0, stream>>>(bsum, nchunks);
    scan_chunk_excl<<<nchunks, 256, 0, stream>>>(deg, bsum, starts, n);
    stage_edges<<<eb, 256, 0, stream>>>(ei, eflag, bcur, staged, e, n);
    fill_csr<<<nbuckets, 256, 0, stream>>>(staged, bcur, starts, csr_src, n);

    // layer 1: hW1 = x@W1 -> hWb (bf16) ; h1 = agg+b1 -> bufH ; bn1
    gemm_mfma<false><<<gg, 256, 0, stream>>>(x, Wt1, nullptr, nullptr, hWb, n);
    aggregate<<<ab, 256, 0, stream>>>(hWb, csr_src, starts, deg, dis, b1, bufH, n);
    hipMemsetAsync(sums, 0, 1024, stream);
    bn_stats<<<512, 256, 0, stream>>>(bufH, sums, n);
    bn_final<<<1, 128, 0, stream>>>(sums, g1, be1, bnp, n);

    // layer 2: hW2 = bnrelu(h1)@W2 -> hWb ; h2 = agg+b2 -> bufH ; bn2
    gemm_mfma<false><<<gg, 256, 0, stream>>>(bufH, Wt2, bnp, nullptr, hWb, n);
    aggregate<<<ab, 256, 0, stream>>>(hWb, csr_src, starts, deg, dis, b2, bufH, n);
    hipMemsetAsync(sums, 0, 1024, stream);
    bn_stats<<<512, 256, 0, stream>>>(bufH, sums, n);
    bn_final<<<1, 128, 0, stream>>>(sums, g2, be2, bnp, n);

    // heads: bnrelu(h2)@[Wmu|Wlv]+[bmu|blv] -> d_out (mu||lv) directly
    gemm_mfma<true><<<gg, 256, 0, stream>>>(bufH, Wtc, bnp, bcat, d_out, n);
}

// Round 17
// 580.360 us; speedup vs baseline: 1.4949x; 1.4949x over previous
//
#include <hip/hip_runtime.h>

// ---------------------------------------------------------------------------
// StructureEncoder — MFMA bf16 GEMMs, CSR gather aggregation (bf16, ILP-16)
// with FUSED BatchNorm statistics (64-copy atomic reduction), single-pass CSR
// build (round-16 bucketed build reverted: 782-cursor atomic contention).
// ---------------------------------------------------------------------------

typedef __attribute__((ext_vector_type(8))) short bf16x8;
typedef __attribute__((ext_vector_type(4))) float f32x4;

#define NCOPY 64   // sums copies for contention-free atomic BN reduction

__device__ inline unsigned short f2bf(float f) {
    unsigned u = __float_as_uint(f);
    unsigned r = u + 0x7FFFu + ((u >> 16) & 1u);   // RNE
    return (unsigned short)(r >> 16);
}
__device__ inline float bf2f(unsigned u16) {
    return __uint_as_float(u16 << 16);
}

__global__ void k_edetect(const int* __restrict__ ei, int n, int* __restrict__ flag) {
    if (threadIdx.x == 0 && blockIdx.x == 0) {
        int is64 = 1;
        for (int i = 0; i < 64; ++i) {
            if (ei[2 * i + 1] != 0 || (unsigned)ei[2 * i] >= (unsigned)n) { is64 = 0; break; }
        }
        *flag = is64;
    }
}

__global__ __launch_bounds__(256) void deg_count(const int* __restrict__ ei,
                                                 const int* __restrict__ eflag,
                                                 unsigned* __restrict__ deg, int e, int n) {
    int i = blockIdx.x * 256 + threadIdx.x;
    if (i >= e) return;
    int d = (*eflag) ? ei[2 * (size_t)e + 2 * (size_t)i] : ei[(size_t)e + i];
    if ((unsigned)d < (unsigned)n) atomicAdd(&deg[d], 1u);
}

__global__ __launch_bounds__(256) void node_init(const unsigned* __restrict__ deg,
                                                 float* __restrict__ dis,
                                                 unsigned* __restrict__ starts,
                                                 unsigned* __restrict__ cursor,
                                                 unsigned* __restrict__ total, int n) {
    int i = blockIdx.x * 256 + threadIdx.x;
    if (i < n) {
        unsigned d = deg[i];
        dis[i] = rsqrtf((float)d + 1.0f);          // degree with self loop
        unsigned s = atomicAdd(total, d);
        starts[i] = s;
        cursor[i] = s;
    }
}

__global__ __launch_bounds__(256) void csr_fill(const int* __restrict__ ei,
                                                const int* __restrict__ eflag,
                                                unsigned* __restrict__ cursor,
                                                int* __restrict__ csr_src, int e, int n) {
    int i = blockIdx.x * 256 + threadIdx.x;
    if (i >= e) return;
    int s, d;
    if (*eflag) {
        s = ei[2 * (size_t)i];
        d = ei[2 * (size_t)e + 2 * (size_t)i];
    } else {
        s = ei[i];
        d = ei[(size_t)e + i];
    }
    if ((unsigned)s >= (unsigned)n || (unsigned)d >= (unsigned)n) return;
    unsigned slot = atomicAdd(&cursor[d], 1u);
    if (slot < (unsigned)e) csr_src[slot] = s;
}

// ---- weight prep: Wt[c][k] = bf16(W[k][c]) for W1, W2, [Wmu|Wlv]; bcat -----

__global__ __launch_bounds__(256) void prep_weights(const float* __restrict__ W1,
                                                    const float* __restrict__ W2,
                                                    const float* __restrict__ Wmu,
                                                    const float* __restrict__ Wlv,
                                                    const float* __restrict__ bmu,
                                                    const float* __restrict__ blv,
                                                    unsigned short* __restrict__ Wt1,
                                                    unsigned short* __restrict__ Wt2,
                                                    unsigned short* __restrict__ Wtc,
                                                    float* __restrict__ bcat) {
    int idx = blockIdx.x * 256 + threadIdx.x;
    if (idx < 16384) {
        int c = idx >> 7, k = idx & 127;
        Wt1[idx] = f2bf(W1[(size_t)k * 128 + c]);
    } else if (idx < 32768) {
        int t = idx - 16384, c = t >> 7, k = t & 127;
        Wt2[t] = f2bf(W2[(size_t)k * 128 + c]);
    } else if (idx < 49152) {
        int t = idx - 32768, c = t >> 7, k = t & 127;
        float v = (c < 64) ? Wmu[(size_t)k * 64 + c] : Wlv[(size_t)k * 64 + (c - 64)];
        Wtc[t] = f2bf(v);
    }
    if (idx < 128) bcat[idx] = (idx < 64) ? bmu[idx] : blv[idx - 64];
}

// ---- aggregation + fused BN stats: 64 nodes per block (grid-stride x16) ----
// out[node] = dis[node]*sum_e dis[src]*hW[src] + dis[node]^2*hW[node] + bias
// Each thread also accumulates s/s^2 for its 2 channels across its 16 nodes,
// then 4 atomicAdds into sums copy (blockIdx & 63): S[copy][ch]=s, [128+ch]=s2.

__global__ __launch_bounds__(256) void aggregate_bn(const unsigned* __restrict__ hWb,
                                                    const int* __restrict__ csr_src,
                                                    const unsigned* __restrict__ starts,
                                                    const unsigned* __restrict__ deg,
                                                    const float* __restrict__ dis,
                                                    const float* __restrict__ bias,
                                                    float* __restrict__ outh,
                                                    float* __restrict__ S, int n) {
    const int nb0  = blockIdx.x * 64;
    const int wv   = threadIdx.x >> 6;
    const int lane = threadIdx.x & 63;
    const float b0 = bias[lane * 2];
    const float b1 = bias[lane * 2 + 1];

    float sl = 0.f, s2l = 0.f, shi = 0.f, s2h = 0.f;

    for (int g = 0; g < 16; ++g) {
        int node = nb0 + g * 4 + wv;
        if (node >= n) break;
        unsigned s0 = starts[node], dn = deg[node];
        float ax = 0.f, ay = 0.f;
        unsigned j = 0;
        for (; j + 16 <= dn; j += 16) {
            int si[16]; unsigned vv[16]; float ww[16];
#pragma unroll
            for (int q = 0; q < 16; ++q) si[q] = csr_src[s0 + j + q];
#pragma unroll
            for (int q = 0; q < 16; ++q) vv[q] = hWb[(size_t)si[q] * 64 + lane];
#pragma unroll
            for (int q = 0; q < 16; ++q) ww[q] = dis[si[q]];
#pragma unroll
            for (int q = 0; q < 16; ++q) {
                ax = fmaf(bf2f(vv[q] & 0xFFFFu), ww[q], ax);
                ay = fmaf(bf2f(vv[q] >> 16), ww[q], ay);
            }
        }
        for (; j + 8 <= dn; j += 8) {
            int si[8]; unsigned vv[8]; float ww[8];
#pragma unroll
            for (int q = 0; q < 8; ++q) si[q] = csr_src[s0 + j + q];
#pragma unroll
            for (int q = 0; q < 8; ++q) vv[q] = hWb[(size_t)si[q] * 64 + lane];
#pragma unroll
            for (int q = 0; q < 8; ++q) ww[q] = dis[si[q]];
#pragma unroll
            for (int q = 0; q < 8; ++q) {
                ax = fmaf(bf2f(vv[q] & 0xFFFFu), ww[q], ax);
                ay = fmaf(bf2f(vv[q] >> 16), ww[q], ay);
            }
        }
        for (; j + 4 <= dn; j += 4) {
            int si[4]; unsigned vv[4]; float ww[4];
#pragma unroll
            for (int q = 0; q < 4; ++q) si[q] = csr_src[s0 + j + q];
#pragma unroll
            for (int q = 0; q < 4; ++q) vv[q] = hWb[(size_t)si[q] * 64 + lane];
#pragma unroll
            for (int q = 0; q < 4; ++q) ww[q] = dis[si[q]];
#pragma unroll
            for (int q = 0; q < 4; ++q) {
                ax = fmaf(bf2f(vv[q] & 0xFFFFu), ww[q], ax);
                ay = fmaf(bf2f(vv[q] >> 16), ww[q], ay);
            }
        }
        for (; j < dn; ++j) {
            int      s = csr_src[s0 + j];
            float    w = dis[s];
            unsigned v = hWb[(size_t)s * 64 + lane];
            ax = fmaf(bf2f(v & 0xFFFFu), w, ax);
            ay = fmaf(bf2f(v >> 16), w, ay);
        }
        float dii = dis[node];
        unsigned vs = hWb[(size_t)node * 64 + lane];
        float rx = fmaf(dii, ax, dii * dii * bf2f(vs & 0xFFFFu)) + b0;
        float ry = fmaf(dii, ay, dii * dii * bf2f(vs >> 16)) + b1;
        *(float2*)(outh + (size_t)node * 128 + lane * 2) = make_float2(rx, ry);
        sl  += rx;  s2l += rx * rx;
        shi += ry;  s2h += ry * ry;
    }

    float* Sc = S + (size_t)(blockIdx.x & (NCOPY - 1)) * 256;
    int ch0 = lane * 2;
    atomicAdd(&Sc[ch0],           sl);
    atomicAdd(&Sc[ch0 + 1],       shi);
    atomicAdd(&Sc[128 + ch0],     s2l);
    atomicAdd(&Sc[128 + ch0 + 1], s2h);
}

__global__ void bn_final(const float* __restrict__ S, const float* __restrict__ g,
                         const float* __restrict__ be, float* __restrict__ bnp, int n) {
    int c = threadIdx.x;                            // 128 threads
    float s = 0.f, s2 = 0.f;
    for (int k = 0; k < NCOPY; ++k) {
        s  += S[k * 256 + c];
        s2 += S[k * 256 + 128 + c];
    }
    float inv_n = 1.0f / (float)n;
    float mean = s * inv_n;
    float var  = s2 * inv_n - mean * mean;
    float sc   = g[c] * rsqrtf(var + 1e-5f);
    bnp[c]       = sc;
    bnp[128 + c] = be[c] - mean * sc;
}

// ---- MFMA GEMM: C[M,128] = bnrelu(A)[M,128] @ W[128,128] -------------------

template <bool HEAD>
__global__ __launch_bounds__(256, 4) void gemm_mfma(const float* __restrict__ A,
                                                    const unsigned short* __restrict__ Wt,
                                                    const float* __restrict__ bnp,
                                                    const float* __restrict__ bias,
                                                    void* __restrict__ Cv, int nrows) {
    __shared__ float Cl[64][130];
    __shared__ float bnsc[128], bnsh[128];

    const int tid  = threadIdx.x;
    const int lane = tid & 63;
    const int wv   = tid >> 6;
    const int rowbase = blockIdx.x * 64;
    const bool has_bn = (bnp != nullptr);
    if (has_bn && tid < 128) {
        bnsc[tid] = bnp[tid];
        bnsh[tid] = bnp[128 + tid];
    }
    __syncthreads();

    const int ar = rowbase + wv * 16 + (lane & 15);
    const int kg = (lane >> 4) * 8;
    const int bc = lane & 15;

    f32x4 acc[8];
#pragma unroll
    for (int t = 0; t < 8; ++t) acc[t] = {0.f, 0.f, 0.f, 0.f};

#pragma unroll
    for (int k0 = 0; k0 < 128; k0 += 32) {
        float va[8];
        if (ar < nrows) {
            float4 a0 = *(const float4*)(A + (size_t)ar * 128 + k0 + kg);
            float4 a1 = *(const float4*)(A + (size_t)ar * 128 + k0 + kg + 4);
            va[0] = a0.x; va[1] = a0.y; va[2] = a0.z; va[3] = a0.w;
            va[4] = a1.x; va[5] = a1.y; va[6] = a1.z; va[7] = a1.w;
        } else {
#pragma unroll
            for (int i = 0; i < 8; ++i) va[i] = 0.f;
        }
        if (has_bn) {
#pragma unroll
            for (int i = 0; i < 8; ++i) {
                int k = k0 + kg + i;
                va[i] = fmaxf(0.f, fmaf(va[i], bnsc[k], bnsh[k]));
            }
        }
        bf16x8 af;
#pragma unroll
        for (int i = 0; i < 8; ++i) af[i] = (short)f2bf(va[i]);

#pragma unroll
        for (int ct = 0; ct < 8; ++ct) {
            bf16x8 bf = *(const bf16x8*)(Wt + (size_t)(ct * 16 + bc) * 128 + k0 + kg);
            acc[ct] = __builtin_amdgcn_mfma_f32_16x16x32_bf16(af, bf, acc[ct], 0, 0, 0);
        }
    }

    const int lr = wv * 16 + ((lane >> 4) << 2);
#pragma unroll
    for (int ct = 0; ct < 8; ++ct)
#pragma unroll
        for (int r = 0; r < 4; ++r)
            Cl[lr + r][ct * 16 + bc] = acc[ct][r];
    __syncthreads();

    const int row = tid >> 2;
    const int c0  = (tid & 3) * 32;
    const int gr  = rowbase + row;
    if (gr < nrows) {
        if (!HEAD) {
            unsigned* C = (unsigned*)Cv;
#pragma unroll
            for (int u = 0; u < 4; ++u) {
                int cb = c0 + u * 8;
                unsigned o0 = (unsigned)f2bf(Cl[row][cb + 0]) | ((unsigned)f2bf(Cl[row][cb + 1]) << 16);
                unsigned o1 = (unsigned)f2bf(Cl[row][cb + 2]) | ((unsigned)f2bf(Cl[row][cb + 3]) << 16);
                unsigned o2 = (unsigned)f2bf(Cl[row][cb + 4]) | ((unsigned)f2bf(Cl[row][cb + 5]) << 16);
                unsigned o3 = (unsigned)f2bf(Cl[row][cb + 6]) | ((unsigned)f2bf(Cl[row][cb + 7]) << 16);
                uint4 o4 = {o0, o1, o2, o3};
                *(uint4*)(C + (size_t)gr * 64 + cb / 2) = o4;
            }
        } else {
            float* mu = (float*)Cv;
            float* lv = mu + (size_t)nrows * 64;
            float* dst = (c0 < 64) ? (mu + (size_t)gr * 64 + c0) : (lv + (size_t)gr * 64 + (c0 - 64));
#pragma unroll
            for (int u = 0; u < 8; ++u) {
                int cb = c0 + u * 4;
                float4 o = make_float4(Cl[row][cb + 0] + bias[cb + 0],
                                       Cl[row][cb + 1] + bias[cb + 1],
                                       Cl[row][cb + 2] + bias[cb + 2],
                                       Cl[row][cb + 3] + bias[cb + 3]);
                *(float4*)(dst + u * 4) = o;
            }
        }
    }
}

// ---------------------------------------------------------------------------

extern "C" void kernel_launch(void* const* d_in, const int* in_sizes, int n_in,
                              void* d_out, int out_size, void* d_ws, size_t ws_size,
                              hipStream_t stream) {
    const float* x   = (const float*)d_in[0];
    const int*   ei  = (const int*)d_in[1];
    const float* W1  = (const float*)d_in[2];
    const float* b1  = (const float*)d_in[3];
    const float* g1  = (const float*)d_in[4];
    const float* be1 = (const float*)d_in[5];
    const float* W2  = (const float*)d_in[6];
    const float* b2  = (const float*)d_in[7];
    const float* g2  = (const float*)d_in[8];
    const float* be2 = (const float*)d_in[9];
    const float* Wmu = (const float*)d_in[10];
    const float* bmu = (const float*)d_in[11];
    const float* Wlv = (const float*)d_in[12];
    const float* blv = (const float*)d_in[13];

    const int n = in_sizes[0] / 128;   // 100000
    const int e = in_sizes[1] / 2;     // 1600000

    char* ws = (char*)d_ws;
    size_t off = 0;
    auto alloc = [&](size_t bytes) {
        void* p = ws + off;
        off = (off + bytes + 255) & ~(size_t)255;
        return p;
    };
    float*          bufH    = (float*)alloc((size_t)n * 128 * 4);
    unsigned*       hWb     = (unsigned*)alloc((size_t)n * 64 * 4);
    int*            csr_src = (int*)alloc((size_t)e * 4);
    unsigned*       deg     = (unsigned*)alloc((size_t)n * 4);
    float*          dis     = (float*)alloc((size_t)n * 4);
    unsigned*       starts  = (unsigned*)alloc((size_t)n * 4);
    unsigned*       cursor  = (unsigned*)alloc((size_t)n * 4);
    unsigned*       total   = (unsigned*)alloc(256);
    int*            eflag   = (int*)alloc(256);
    float*          S       = (float*)alloc((size_t)NCOPY * 256 * 4);   // 64KB
    float*          bnp     = (float*)alloc(256 * 4);
    unsigned short* Wt1     = (unsigned short*)alloc(16384 * 2);
    unsigned short* Wt2     = (unsigned short*)alloc(16384 * 2);
    unsigned short* Wtc     = (unsigned short*)alloc(16384 * 2);
    float*          bcat    = (float*)alloc(128 * 4);

    const int eb = (e + 255) / 256;
    const int nb = (n + 255) / 256;
    const int ag = (n + 63) / 64;
    const int gg = (n + 63) / 64;

    // prep: weights, graph CSR (single-pass, node-cursor)
    hipMemsetAsync(deg, 0, (size_t)n * 4, stream);
    hipMemsetAsync(total, 0, 4, stream);
    prep_weights<<<192, 256, 0, stream>>>(W1, W2, Wmu, Wlv, bmu, blv, Wt1, Wt2, Wtc, bcat);
    k_edetect<<<1, 64, 0, stream>>>(ei, n, eflag);
    deg_count<<<eb, 256, 0, stream>>>(ei, eflag, deg, e, n);
    node_init<<<nb, 256, 0, stream>>>(deg, dis, starts, cursor, total, n);
    csr_fill<<<eb, 256, 0, stream>>>(ei, eflag, cursor, csr_src, e, n);

    // layer 1: hW1 = x@W1 -> hWb (bf16) ; h1 = agg+b1 -> bufH (+BN stats) ; bn1
    gemm_mfma<false><<<gg, 256, 0, stream>>>(x, Wt1, nullptr, nullptr, hWb, n);
    hipMemsetAsync(S, 0, (size_t)NCOPY * 256 * 4, stream);
    aggregate_bn<<<ag, 256, 0, stream>>>(hWb, csr_src, starts, deg, dis, b1, bufH, S, n);
    bn_final<<<1, 128, 0, stream>>>(S, g1, be1, bnp, n);

    // layer 2: hW2 = bnrelu(h1)@W2 -> hWb ; h2 = agg+b2 -> bufH (+BN stats) ; bn2
    gemm_mfma<false><<<gg, 256, 0, stream>>>(bufH, Wt2, bnp, nullptr, hWb, n);
    hipMemsetAsync(S, 0, (size_t)NCOPY * 256 * 4, stream);
    aggregate_bn<<<ag, 256, 0, stream>>>(hWb, csr_src, starts, deg, dis, b2, bufH, S, n);
    bn_final<<<1, 128, 0, stream>>>(S, g2, be2, bnp, n);

    // heads: bnrelu(h2)@[Wmu|Wlv]+[bmu|blv] -> d_out (mu||lv) directly
    gemm_mfma<true><<<gg, 256, 0, stream>>>(bufH, Wtc, bnp, bcat, d_out, n);
}